// Round 17
// baseline (106.876 us; speedup 1.0000x reference)
//
#include <hip/hip_runtime.h>

// LabelizerNet: avg-pool(6,2) -> RGB->HSV -> yellow/blue mask -> per-panel max/min
// Input : states (N, 3, 84, 84) f32   (N = 4096)
// Output: labels (N, 6) f32  [yellow panels 0..2, blue panels 0..2]
//
// Round 17: r14's proven pipeline (73.3 us) with DUAL READ PATHS: channels 0,1
// via global_load_lds DMA double-buffer (counted vmcnt, never drained mid-loop);
// channel 2 read directly from global inside compute (separate miss-tracking
// pool hypothesis). LDS halves to 32.8 KB -> 4 blocks/CU. Summation tree and
// HSV math verbatim -> bit-identical results.

#define CH_ELEMS 7056              // 84*84
#define IMG_FLT  21168             // 3*7056
#define IMG_F4   5292
#define CH_F4    1764              // 7056/4
#define Q_F4     504               // 24 rows * 21 f4 per channel
#define SLOT_F4  512               // per-channel slot (8-f4 slack)
#define BUF_F4   1024              // 2 channels per buffer
#define ROW_STR  84

__device__ __forceinline__ void gl_lds16(const float4* g, float4* l) {
    __builtin_amdgcn_global_load_lds(
        (const __attribute__((address_space(1))) void*)(uintptr_t)(const void*)g,
        (__attribute__((address_space(3))) void*)(uintptr_t)(void*)l,
        16, 0, 0);
}

__global__ __launch_bounds__(256)
void labelizer_fused(const float* __restrict__ in, float* __restrict__ out) {
    __shared__ float4 s4[2 * BUF_F4];      // 32768 B
    __shared__ unsigned bmask;

    const int tid = threadIdx.x;
    const int img = blockIdx.x;
    const int wid = tid >> 6, lane = tid & 63;
    if (tid == 0) bmask = 0u;

    const float4* base = (const float4*)in + (size_t)img * IMG_F4;
    unsigned my = 0u;

    // ---- stage channels 0,1 of quarter q (rows 20q..20q+23): 4 DMA/wave ----
    auto stage01 = [&](int q, int b) {
        const float4* sq = base + q * 20 * 21;
        float4* db = s4 + b * BUF_F4;
        #pragma unroll
        for (int c = 0; c < 2; ++c) {
            const float4* sc = sq + c * CH_F4;
            float4* dc = db + c * SLOT_F4;
            #pragma unroll
            for (int k = 0; k < 2; ++k) {
                int i = (wid + 4 * k) * 64 + lane;       // 8 chunks x 64 f4
                gl_lds16(sc + min(i, Q_F4 - 1), dc + i); // src clamped; dest lane-linear
            }
        }
    };

    // ---- compute quarter q from buffer b (c0,c1 LDS; c2 direct global) ----
    auto compute = [&](int q, int b) {
        if (tid < 200) {
            const int pr = tid / 20;             // pooled row within quarter
            const int xp = tid - pr * 20;        // pair-column 0..19
            const int x0 = 2 * xp, x1 = 2 * xp + 1;
            const float* sf = (const float*)(s4 + b * BUF_F4);
            const int lbase = (2 * pr) * ROW_STR + 4 * xp;
            const float* g2 = in + (size_t)img * IMG_FLT + 2 * CH_ELEMS
                            + (20 * q + 2 * pr) * ROW_STR + 4 * xp;

            float t0[3], t1[3];
            #pragma unroll
            for (int c = 0; c < 3; ++c) {
                float P0[3], P1[3];
                #pragma unroll
                for (int j = 0; j < 3; ++j) {
                    const float4 *ra, *rb;
                    if (c < 2) {
                        const float* rbase = sf + c * (4 * SLOT_F4) + lbase + (2 * j) * ROW_STR;
                        ra = (const float4*)rbase;
                        rb = (const float4*)(rbase + ROW_STR);
                    } else {
                        const float* rbase = g2 + (2 * j) * ROW_STR;
                        ra = (const float4*)rbase;
                        rb = (const float4*)(rbase + ROW_STR);
                    }
                    float4 qa0 = ra[0], qa1 = ra[1];
                    float4 qb0 = rb[0], qb1 = rb[1];
                    float a01 = qa0.x + qa0.y, a23 = qa0.z + qa0.w;
                    float a45 = qa1.x + qa1.y, a67 = qa1.z + qa1.w;
                    float rsa0 = (a01 + a23) + a45;      // rs[2j],  window x0
                    float rsa1 = (a23 + a45) + a67;      // rs[2j],  window x1
                    float b01 = qb0.x + qb0.y, b23 = qb0.z + qb0.w;
                    float b45 = qb1.x + qb1.y, b67 = qb1.z + qb1.w;
                    float rsb0 = (b01 + b23) + b45;      // rs[2j+1], window x0
                    float rsb1 = (b23 + b45) + b67;      // rs[2j+1], window x1
                    P0[j] = rsa0 + rsb0;                 // pair sum
                    P1[j] = rsa1 + rsb1;
                }
                t0[c] = (P0[0] + P0[1]) + P0[2];     // == ((rs0+rs1)+(rs2+rs3))+(rs4+rs5)
                t1[c] = (P1[0] + P1[1]) + P1[2];
            }

            #pragma unroll
            for (int e = 0; e < 2; ++e) {
                float r = ((e == 0) ? t0[0] : t1[0]) / 36.0f;
                float g = ((e == 0) ? t0[1] : t1[1]) / 36.0f;
                float bb = ((e == 0) ? t0[2] : t1[2]) / 36.0f;

                float maxc = fmaxf(r, fmaxf(g, bb));
                float minc = fminf(r, fminf(g, bb));
                float delta = maxc - minc;
                float s = (maxc == 0.0f) ? 0.0f : delta / maxc;
                float v = maxc;
                float h = 0.0f;
                if (delta != 0.0f) {
                    float rc = (maxc - r) / delta;
                    float gc = (maxc - g) / delta;
                    float bc = (maxc - bb) / delta;
                    float hh = (r == maxc) ? (bc - gc)
                             : ((g == maxc) ? (2.0f + rc - bc)
                                            : (4.0f + gc - rc));
                    h = hh / 6.0f;           // in (-1/6, 5/6); floor-mod 1:
                    if (h < 0.0f) h += 1.0f;
                }
                bool satval = (s > 0.5f) && (v > 0.5f);
                int m = 0;
                if (satval && h >= 0.1f && h <= 0.2f) m = 1;
                else if (satval && h >= 0.55f && h <= 0.7f) m = -1;

                int x = (e == 0) ? x0 : x1;
                if (x < 39) {                 // col 39 excluded (40//3*3 == 39)
                    int pan = x / 13;         // 0..2
                    unsigned bit = (m > 0) ? 1u : (m < 0) ? 2u : 4u;
                    my |= bit << (3 * pan);
                }
            }
        }
    };

    // ---- pipeline: stage Q0; {stage Q(q+1) | vmcnt(4) | compute Q(q)} x4 ----
    stage01(0, 0);
    __syncthreads();                         // drain prologue, publish bmask=0

    #pragma unroll
    for (int q = 0; q < 4; ++q) {
        if (q < 3) {
            stage01(q + 1, (q + 1) & 1);     // 4 more DMA/wave in flight
            asm volatile("s_waitcnt vmcnt(4)" ::: "memory");   // Q(q) landed, Q(q+1) flying
        } else {
            asm volatile("s_waitcnt vmcnt(0)" ::: "memory");   // last tile: full drain
        }
        __builtin_amdgcn_s_barrier();        // all waves' Q(q) visible
        compute(q, q & 1);
        __builtin_amdgcn_s_barrier();        // all readers done before buf reuse
    }

    // ---- in-block reduce -> direct output write ----
    #pragma unroll
    for (int off = 32; off > 0; off >>= 1) my |= __shfl_xor(my, off);
    if ((tid & 63) == 0 && my) atomicOr(&bmask, my);
    __syncthreads();

    if (tid < 6) {
        int pan = (tid < 3) ? tid : tid - 3;
        unsigned w = bmask >> (3 * pan);
        bool anyY = w & 1u;
        bool anyB = (w >> 1) & 1u;
        bool anyZ = (w >> 2) & 1u;
        float val;
        if (tid < 3) val = anyY ? 1.0f : (anyZ ? 0.0f : -1.0f);   // max(panel)
        else         val = anyB ? 1.0f : (anyZ ? 0.0f : -1.0f);   // -min(panel)
        out[(size_t)img * 6 + tid] = val;
    }
}

extern "C" void kernel_launch(void* const* d_in, const int* in_sizes, int n_in,
                              void* d_out, int out_size, void* d_ws, size_t ws_size,
                              hipStream_t stream) {
    const float* states = (const float*)d_in[0];
    float* out = (float*)d_out;
    int N = in_sizes[0] / (3 * CH_ELEMS);   // 4096
    labelizer_fused<<<N, 256, 0, stream>>>(states, out);
}

// Round 18
// 75.763 us; speedup vs baseline: 1.4107x; 1.4107x over previous
//
#include <hip/hip_runtime.h>

// LabelizerNet: avg-pool(6,2) -> RGB->HSV -> yellow/blue mask -> per-panel max/min
// Input : states (N, 3, 84, 84) f32   (N = 4096)
// Output: labels (N, 6) f32  [yellow panels 0..2, blue panels 0..2]
//
// Round 18: r14's proven counted-vmcnt quarter pipeline (73.3 us), made
// persistent over IPB=2 images: one continuous 8-tile pipeline per block,
// next image's Q0 stages during q=3's compute -- the DMA queue never drains
// mid-block (r14 paid a full drain prologue per image). Stage geometry,
// vmcnt(6) discipline, and compute math verbatim r14 -> bit-identical.

#define CH_ELEMS 7056              // 84*84
#define IMG_F4   5292              // 3*7056/4
#define CH_F4    1764              // 7056/4
#define Q_F4     504               // 24 rows * 21 f4 staged per channel
#define SLOT_F4  512               // channel slot in LDS (8-f4 overrun gap)
#define BUF_F4   1536              // 3 * SLOT_F4 per buffer
#define ROW_STR  84                // floats per row in LDS
#define IPB      2
#define NTILES   (4 * IPB)

__device__ __forceinline__ void gl_lds16(const float4* g, float4* l) {
    __builtin_amdgcn_global_load_lds(
        (const __attribute__((address_space(1))) void*)(uintptr_t)(const void*)g,
        (__attribute__((address_space(3))) void*)(uintptr_t)(void*)l,
        16, 0, 0);
}

__global__ __launch_bounds__(256)
void labelizer_fused(const float* __restrict__ in, float* __restrict__ out) {
    __shared__ float4 s4[2 * BUF_F4];      // 49152 B
    __shared__ unsigned smu[4];

    const int tid = threadIdx.x;
    const int img0 = blockIdx.x * IPB;
    const int wid = tid >> 6, lane = tid & 63;

    const float4* base = (const float4*)in;
    unsigned my = 0u;

    // ---- stage tile t (image img0+t/4, quarter t%4) into buffer b: 6 DMA/wave ----
    auto stage = [&](int t, int b) {
        const float4* sq = base + (size_t)(img0 + (t >> 2)) * IMG_F4 + (t & 3) * 20 * 21;
        float4* db = s4 + b * BUF_F4;
        #pragma unroll
        for (int c = 0; c < 3; ++c) {
            const float4* sc = sq + c * CH_F4;
            float4* dc = db + c * SLOT_F4;
            #pragma unroll
            for (int k = 0; k < 2; ++k) {
                int i = (wid + 4 * k) * 64 + lane;       // 8 chunks x 64 f4
                gl_lds16(sc + min(i, Q_F4 - 1), dc + i); // src clamped; dest lane-linear
            }
        }
    };

    // ---- compute quarter from buffer b (verbatim r14) ----
    auto compute = [&](int b) {
        if (tid < 200) {
            const int pr = tid / 20;             // pooled row within quarter
            const int xp = tid - pr * 20;        // pair-column 0..19
            const int x0 = 2 * xp, x1 = 2 * xp + 1;
            const float* sf = (const float*)(s4 + b * BUF_F4);
            const int lbase = (2 * pr) * ROW_STR + 4 * xp;

            float t0[3], t1[3];
            #pragma unroll
            for (int c = 0; c < 3; ++c) {
                float P0[3], P1[3];
                #pragma unroll
                for (int j = 0; j < 3; ++j) {
                    const float* rbase = sf + c * (4 * SLOT_F4) + lbase + (2 * j) * ROW_STR;
                    const float4* ra = (const float4*)rbase;
                    const float4* rb = (const float4*)(rbase + ROW_STR);
                    float4 qa0 = ra[0], qa1 = ra[1];
                    float4 qb0 = rb[0], qb1 = rb[1];
                    float a01 = qa0.x + qa0.y, a23 = qa0.z + qa0.w;
                    float a45 = qa1.x + qa1.y, a67 = qa1.z + qa1.w;
                    float rsa0 = (a01 + a23) + a45;      // rs[2j],  window x0
                    float rsa1 = (a23 + a45) + a67;      // rs[2j],  window x1
                    float b01 = qb0.x + qb0.y, b23 = qb0.z + qb0.w;
                    float b45 = qb1.x + qb1.y, b67 = qb1.z + qb1.w;
                    float rsb0 = (b01 + b23) + b45;      // rs[2j+1], window x0
                    float rsb1 = (b23 + b45) + b67;      // rs[2j+1], window x1
                    P0[j] = rsa0 + rsb0;                 // pair sum
                    P1[j] = rsa1 + rsb1;
                }
                t0[c] = (P0[0] + P0[1]) + P0[2];     // == ((rs0+rs1)+(rs2+rs3))+(rs4+rs5)
                t1[c] = (P1[0] + P1[1]) + P1[2];
            }

            #pragma unroll
            for (int e = 0; e < 2; ++e) {
                float r = ((e == 0) ? t0[0] : t1[0]) / 36.0f;
                float g = ((e == 0) ? t0[1] : t1[1]) / 36.0f;
                float bb = ((e == 0) ? t0[2] : t1[2]) / 36.0f;

                float maxc = fmaxf(r, fmaxf(g, bb));
                float minc = fminf(r, fminf(g, bb));
                float delta = maxc - minc;
                float s = (maxc == 0.0f) ? 0.0f : delta / maxc;
                float v = maxc;
                float h = 0.0f;
                if (delta != 0.0f) {
                    float rc = (maxc - r) / delta;
                    float gc = (maxc - g) / delta;
                    float bc = (maxc - bb) / delta;
                    float hh = (r == maxc) ? (bc - gc)
                             : ((g == maxc) ? (2.0f + rc - bc)
                                            : (4.0f + gc - rc));
                    h = hh / 6.0f;           // in (-1/6, 5/6); floor-mod 1:
                    if (h < 0.0f) h += 1.0f;
                }
                bool satval = (s > 0.5f) && (v > 0.5f);
                int m = 0;
                if (satval && h >= 0.1f && h <= 0.2f) m = 1;
                else if (satval && h >= 0.55f && h <= 0.7f) m = -1;

                int x = (e == 0) ? x0 : x1;
                if (x < 39) {                 // col 39 excluded (40//3*3 == 39)
                    int pan = x / 13;         // 0..2
                    unsigned bit = (m > 0) ? 1u : (m < 0) ? 2u : 4u;
                    my |= bit << (3 * pan);
                }
            }
        }
    };

    // ---- continuous 8-tile pipeline ----
    stage(0, 0);
    __syncthreads();                         // single prologue drain per block

    #pragma unroll
    for (int t = 0; t < NTILES; ++t) {
        if (t < NTILES - 1) {
            stage(t + 1, (t + 1) & 1);       // 6 more DMA/wave in flight
            asm volatile("s_waitcnt vmcnt(6)" ::: "memory");   // tile t landed, t+1 flying
        } else {
            asm volatile("s_waitcnt vmcnt(0)" ::: "memory");   // last tile: full drain
        }
        __builtin_amdgcn_s_barrier();        // all waves' tile t visible
        compute(t & 1);

        if ((t & 3) == 3) {
            // image end: per-wave reduce -> smu -> write 6 floats
            unsigned r = my;
            #pragma unroll
            for (int off = 32; off > 0; off >>= 1) r |= __shfl_xor(r, off);
            if (lane == 0) smu[wid] = r;
            __syncthreads();                 // doubles as trailing barrier (full drain ok: DMA for t+1 unaffected? vmcnt... see note)
            if (tid < 6) {
                unsigned m4 = smu[0] | smu[1] | smu[2] | smu[3];
                int pan = (tid < 3) ? tid : tid - 3;
                unsigned w = m4 >> (3 * pan);
                bool anyY = w & 1u;
                bool anyB = (w >> 1) & 1u;
                bool anyZ = (w >> 2) & 1u;
                float val;
                if (tid < 3) val = anyY ? 1.0f : (anyZ ? 0.0f : -1.0f);   // max(panel)
                else         val = anyB ? 1.0f : (anyZ ? 0.0f : -1.0f);   // -min(panel)
                out[(size_t)(img0 + (t >> 2)) * 6 + tid] = val;
            }
            my = 0u;
            // NOTE: __syncthreads drains vmcnt(0) -- this re-introduces one drain
            // at the img0 boundary only (t=3); t=7 needed it anyway. Net: one
            // mid-block drain per 2 images vs r14's one per image.
        } else {
            __builtin_amdgcn_s_barrier();    // all readers done before buf reuse
        }
    }
}

extern "C" void kernel_launch(void* const* d_in, const int* in_sizes, int n_in,
                              void* d_out, int out_size, void* d_ws, size_t ws_size,
                              hipStream_t stream) {
    const float* states = (const float*)d_in[0];
    float* out = (float*)d_out;
    int N = in_sizes[0] / (3 * CH_ELEMS);   // 4096
    labelizer_fused<<<N / IPB, 256, 0, stream>>>(states, out);
}

// Round 19
// 73.262 us; speedup vs baseline: 1.4588x; 1.0341x over previous
//
#include <hip/hip_runtime.h>

// LabelizerNet: avg-pool(6,2) -> RGB->HSV -> yellow/blue mask -> per-panel max/min
// Input : states (N, 3, 84, 84) f32   (N = 4096)
// Output: labels (N, 6) f32  [yellow panels 0..2, blue panels 0..2]
//
// FINAL (= round 14, the champion at 73.3 us): fused single kernel, block =
// one image. Quarter-tiles (24 rows) double-buffered in LDS (2 x 24 KB ->
// 3 blocks/CU), staged 100% via global_load_lds (DMA path sustains ~5.6 TB/s
// vs ~3.3 TB/s for VGPR-return loads) with a COUNTED vmcnt pipeline: stage
// Q(q+1) issues before compute Q(q); s_waitcnt vmcnt(6) + raw s_barrier keep
// prefetch loads in flight across barriers (never drain to 0 mid-loop).
// In-block LDS reduce -> direct output write. Levers tested and rejected:
// occupancy x2 (null), zero-overfetch (negative), nt loads (negative),
// dual read paths (negative), cross-image persistence (null).
// Math bit-identical to the reference float-op order throughout.

#define CH_ELEMS 7056              // 84*84
#define IMG_F4   5292              // 3*7056/4
#define CH_F4    1764              // 7056/4
#define ROW_F4   21                // 84/4
#define Q_F4     504               // 24 rows * 21 f4 staged per channel
#define SLOT_F4  512               // channel slot in LDS (8-f4 overrun gap)
#define BUF_F4   1536              // 3 * SLOT_F4 per buffer
#define ROW_STR  84                // floats per row in LDS

__device__ __forceinline__ void gl_lds16(const float4* g, float4* l) {
    __builtin_amdgcn_global_load_lds(
        (const __attribute__((address_space(1))) void*)(uintptr_t)(const void*)g,
        (__attribute__((address_space(3))) void*)(uintptr_t)(void*)l,
        16, 0, 0);
}

__global__ __launch_bounds__(256)
void labelizer_fused(const float* __restrict__ in, float* __restrict__ out) {
    __shared__ float4 s4[2 * BUF_F4];      // 49152 B
    __shared__ unsigned bmask;

    const int tid = threadIdx.x;
    const int img = blockIdx.x;
    const int wid = tid >> 6, lane = tid & 63;
    if (tid == 0) bmask = 0u;

    const float4* base = (const float4*)in + (size_t)img * IMG_F4;
    unsigned my = 0u;

    // ---- stage quarter q (input rows 20q..20q+23) into buffer b: 6 DMA/wave ----
    auto stage = [&](int q, int b) {
        const float4* sq = base + q * 20 * ROW_F4;
        float4* db = s4 + b * BUF_F4;
        #pragma unroll
        for (int c = 0; c < 3; ++c) {
            const float4* sc = sq + c * CH_F4;
            float4* dc = db + c * SLOT_F4;
            #pragma unroll
            for (int k = 0; k < 2; ++k) {
                int i = (wid + 4 * k) * 64 + lane;       // 8 chunks x 64 f4
                gl_lds16(sc + min(i, Q_F4 - 1), dc + i); // src clamped; dest lane-linear
            }
        }
    };

    // ---- compute quarter from buffer b (thread = pooled row pr x pair-col xp) ----
    auto compute = [&](int b) {
        if (tid < 200) {
            const int pr = tid / 20;             // 0..9
            const int xp = tid - pr * 20;        // 0..19
            const int x0 = 2 * xp, x1 = 2 * xp + 1;
            const float* sf = (const float*)(s4 + b * BUF_F4);
            const int lbase = (2 * pr) * ROW_STR + 4 * xp;

            float t0[3], t1[3];
            #pragma unroll
            for (int c = 0; c < 3; ++c) {
                float P0[3], P1[3];
                #pragma unroll
                for (int j = 0; j < 3; ++j) {
                    const float* rbase = sf + c * (4 * SLOT_F4) + lbase + (2 * j) * ROW_STR;
                    const float4* ra = (const float4*)rbase;
                    const float4* rb = (const float4*)(rbase + ROW_STR);
                    float4 qa0 = ra[0], qa1 = ra[1];
                    float4 qb0 = rb[0], qb1 = rb[1];
                    float a01 = qa0.x + qa0.y, a23 = qa0.z + qa0.w;
                    float a45 = qa1.x + qa1.y, a67 = qa1.z + qa1.w;
                    float rsa0 = (a01 + a23) + a45;
                    float rsa1 = (a23 + a45) + a67;
                    float b01 = qb0.x + qb0.y, b23 = qb0.z + qb0.w;
                    float b45 = qb1.x + qb1.y, b67 = qb1.z + qb1.w;
                    float rsb0 = (b01 + b23) + b45;
                    float rsb1 = (b23 + b45) + b67;
                    P0[j] = rsa0 + rsb0;
                    P1[j] = rsa1 + rsb1;
                }
                t0[c] = (P0[0] + P0[1]) + P0[2];     // == ((rs0+rs1)+(rs2+rs3))+(rs4+rs5)
                t1[c] = (P1[0] + P1[1]) + P1[2];
            }

            #pragma unroll
            for (int e = 0; e < 2; ++e) {
                float r = ((e == 0) ? t0[0] : t1[0]) / 36.0f;
                float g = ((e == 0) ? t0[1] : t1[1]) / 36.0f;
                float bb = ((e == 0) ? t0[2] : t1[2]) / 36.0f;

                float maxc = fmaxf(r, fmaxf(g, bb));
                float minc = fminf(r, fminf(g, bb));
                float delta = maxc - minc;
                float s = (maxc == 0.0f) ? 0.0f : delta / maxc;
                float v = maxc;
                float h = 0.0f;
                if (delta != 0.0f) {
                    float rc = (maxc - r) / delta;
                    float gc = (maxc - g) / delta;
                    float bc = (maxc - bb) / delta;
                    float hh = (r == maxc) ? (bc - gc)
                             : ((g == maxc) ? (2.0f + rc - bc)
                                            : (4.0f + gc - rc));
                    h = hh / 6.0f;           // in (-1/6, 5/6); floor-mod 1:
                    if (h < 0.0f) h += 1.0f;
                }
                bool satval = (s > 0.5f) && (v > 0.5f);
                int m = 0;
                if (satval && h >= 0.1f && h <= 0.2f) m = 1;
                else if (satval && h >= 0.55f && h <= 0.7f) m = -1;

                int x = (e == 0) ? x0 : x1;
                if (x < 39) {                 // col 39 excluded (40//3*3 == 39)
                    int pan = x / 13;         // 0..2
                    unsigned bit = (m > 0) ? 1u : (m < 0) ? 2u : 4u;
                    my |= bit << (3 * pan);
                }
            }
        }
    };

    // ---- pipeline: stage Q0; {stage Q(q+1) | wait Q(q) | compute Q(q)} x4 ----
    stage(0, 0);
    __syncthreads();                         // drain prologue (vmcnt 0), publish bmask

    #pragma unroll
    for (int q = 0; q < 4; ++q) {
        if (q < 3) {
            stage(q + 1, (q + 1) & 1);       // 6 more DMA/wave in flight
            asm volatile("s_waitcnt vmcnt(6)" ::: "memory");   // Q(q) landed, Q(q+1) flying
        } else {
            asm volatile("s_waitcnt vmcnt(0)" ::: "memory");   // last tile: full drain
        }
        __builtin_amdgcn_s_barrier();        // all waves' Q(q) visible
        compute(q & 1);
        __builtin_amdgcn_s_barrier();        // all readers done before buf reuse
    }

    // ---- in-block reduce -> direct output write ----
    #pragma unroll
    for (int off = 32; off > 0; off >>= 1) my |= __shfl_xor(my, off);
    if ((tid & 63) == 0 && my) atomicOr(&bmask, my);
    __syncthreads();

    if (tid < 6) {
        int pan = (tid < 3) ? tid : tid - 3;
        unsigned w = bmask >> (3 * pan);
        bool anyY = w & 1u;
        bool anyB = (w >> 1) & 1u;
        bool anyZ = (w >> 2) & 1u;
        float val;
        if (tid < 3) val = anyY ? 1.0f : (anyZ ? 0.0f : -1.0f);   // max(panel)
        else         val = anyB ? 1.0f : (anyZ ? 0.0f : -1.0f);   // -min(panel)
        out[(size_t)img * 6 + tid] = val;
    }
}

extern "C" void kernel_launch(void* const* d_in, const int* in_sizes, int n_in,
                              void* d_out, int out_size, void* d_ws, size_t ws_size,
                              hipStream_t stream) {
    const float* states = (const float*)d_in[0];
    float* out = (float*)d_out;
    int N = in_sizes[0] / (3 * CH_ELEMS);   // 4096
    labelizer_fused<<<N, 256, 0, stream>>>(states, out);
}